// Round 12
// baseline (158.761 us; speedup 1.0000x reference)
//
#include <hip/hip_runtime.h>

#define BATCH    2048
#define FLAT_IN  512
#define PROJ_DIM 256
#define HEADS    16384
#define ACT_DIM  64

typedef __attribute__((ext_vector_type(8))) short short8;   // 8 bf16/f16 bits
typedef _Float16 half8 __attribute__((ext_vector_type(8))); // 8 f16 (4 VGPR)
typedef __attribute__((ext_vector_type(4))) float floatx4;  // MFMA C/D

__device__ __forceinline__ unsigned short f2bf(float x) {
  unsigned u = __float_as_uint(x);
  u += 0x7fff + ((u >> 16) & 1);
  return (unsigned short)(u >> 16);
}
__device__ __forceinline__ float bf2f(unsigned short b) {
  return __uint_as_float(((unsigned)b) << 16);
}
__device__ __forceinline__ unsigned short f2h(float x) {
  _Float16 h = (_Float16)x;   // RNE
  return __builtin_bit_cast(unsigned short, h);
}

#define GLDS16(g, l)                                                          \
  __builtin_amdgcn_global_load_lds(                                           \
      (__attribute__((address_space(1))) void*)(void*)(g),                    \
      (__attribute__((address_space(3))) void*)(l), 16, 0, 0)

// ---------------------------------------------------------------------------
// prep: ONLY rp transpose+split (32 blocks). rp [512][256] -> rpT_hi/mid.
// ---------------------------------------------------------------------------
__global__ __launch_bounds__(256) void prep(
    const float* __restrict__ rp,
    unsigned short* __restrict__ rpT_hi, unsigned short* __restrict__ rpT_mid)
{
  __shared__ float t[64][65];
  const int tid = threadIdx.x;
  int bid = blockIdx.x;
  int k0 = (bid >> 2) * 64, n0 = (bid & 3) * 64;
#pragma unroll
  for (int it = 0; it < 16; ++it) {
    int lin = it * 256 + tid;
    int kr = lin >> 6, nc = lin & 63;
    t[kr][nc] = rp[(size_t)(k0 + kr) * PROJ_DIM + n0 + nc];
  }
  __syncthreads();
#pragma unroll
  for (int it = 0; it < 16; ++it) {
    int lin = it * 256 + tid;
    int nr = lin >> 6, kc = lin & 63;
    float v = t[kc][nr];
    unsigned short hh = f2bf(v);
    rpT_hi [(size_t)(n0 + nr) * FLAT_IN + k0 + kc] = hh;
    rpT_mid[(size_t)(n0 + nr) * FLAT_IN + k0 + kc] = f2bf(v - bf2f(hh));
  }
}

// ---------------------------------------------------------------------------
// gemm_conv: blocks [0,128) = gemm (R8-proven body: raw fp32 state staged via
// GLDS, hi/mid split in VALU; rpT bf16 planes via GLDS; 3-term split-bf16
// MFMA; tile 64x64, BK=64). blocks [128,2176) = mem fp32 -> f16 conversion.
// ---------------------------------------------------------------------------
__global__ __launch_bounds__(256, 2) void gemm_conv(
    const float* __restrict__ state,
    const unsigned short* __restrict__ Bhi, const unsigned short* __restrict__ Bmid,
    const float* __restrict__ mem,
    float* __restrict__ S, unsigned short* __restrict__ Sf16,
    unsigned short* __restrict__ mem_f16)
{
  const int tid = threadIdx.x;
  if (blockIdx.x >= 128) {
    int i2 = (blockIdx.x - 128) * 256 + tid;   // 8-float granule index
    float4 x = ((const float4*)mem)[2 * i2];
    float4 y = ((const float4*)mem)[2 * i2 + 1];
    short8 o;
    o[0] = (short)f2h(x.x); o[1] = (short)f2h(x.y);
    o[2] = (short)f2h(x.z); o[3] = (short)f2h(x.w);
    o[4] = (short)f2h(y.x); o[5] = (short)f2h(y.y);
    o[6] = (short)f2h(y.z); o[7] = (short)f2h(y.w);
    ((short8*)mem_f16)[i2] = o;
    return;
  }

  __shared__ __align__(16) float          smA [64 * 64];   // fp32, 16 KB
  __shared__ __align__(16) unsigned short smBh[64 * 64];   // 8 KB
  __shared__ __align__(16) unsigned short smBm[64 * 64];   // 8 KB
  const int lane = tid & 63, w = tid >> 6;
  const int quad = lane >> 4, col = lane & 15;
  const int wm = (w >> 1) * 32, wn = (w & 1) * 32;
  const int g = blockIdx.x;
  const int m0 = (g & 31) * 64, n0 = (g >> 5) * 64;

  floatx4 acc[2][2];
#pragma unroll
  for (int i = 0; i < 2; ++i)
#pragma unroll
    for (int j = 0; j < 2; ++j) {
      acc[i][j][0] = 0.f; acc[i][j][1] = 0.f;
      acc[i][j][2] = 0.f; acc[i][j][3] = 0.f;
    }

  const int PB0 = tid, PB1 = tid + 256;
  const int rb0 = PB0 >> 3, kb0 = (PB0 & 7) ^ (rb0 & 7);
  const int rb1 = PB1 >> 3, kb1 = (PB1 & 7) ^ (rb1 & 7);

  for (int kc = 0; kc < FLAT_IN; kc += 64) {
#pragma unroll
    for (int t = 0; t < 4; ++t) {
      int P = t * 256 + tid;
      int row = P >> 4;
      int klog = (P & 15) ^ (row & 15);
      GLDS16(state + (size_t)(m0 + row) * FLAT_IN + kc + klog * 4, &smA[P * 4]);
    }
    GLDS16(Bhi  + (size_t)(n0 + rb0) * FLAT_IN + kc + kb0 * 8, &smBh[PB0 * 8]);
    GLDS16(Bhi  + (size_t)(n0 + rb1) * FLAT_IN + kc + kb1 * 8, &smBh[PB1 * 8]);
    GLDS16(Bmid + (size_t)(n0 + rb0) * FLAT_IN + kc + kb0 * 8, &smBm[PB0 * 8]);
    GLDS16(Bmid + (size_t)(n0 + rb1) * FLAT_IN + kc + kb1 * 8, &smBm[PB1 * 8]);
    __syncthreads();

#pragma unroll
    for (int ks = 0; ks < 2; ++ks) {
      short8 bf[2][2];
#pragma unroll
      for (int j = 0; j < 2; ++j) {
        int rr = wn + j * 16 + col;
        int off = rr * 64 + (((ks * 4 + quad) ^ (rr & 7)) * 8);
        bf[j][0] = *(const short8*)&smBh[off];
        bf[j][1] = *(const short8*)&smBm[off];
      }
#pragma unroll
      for (int i = 0; i < 2; ++i) {
        int rr = wm + i * 16 + col;
        int s0 = ks * 8 + quad * 2;           // logical 4-float slot pair
        float4 f0 = *(const float4*)&smA[rr * 64 + ((s0     ^ (rr & 15)) * 4)];
        float4 f1 = *(const float4*)&smA[rr * 64 + (((s0+1) ^ (rr & 15)) * 4)];
        float f[8] = {f0.x, f0.y, f0.z, f0.w, f1.x, f1.y, f1.z, f1.w};
        short8 a0, a1;
#pragma unroll
        for (int q = 0; q < 8; ++q) {
          unsigned short hh = f2bf(f[q]);
          a0[q] = (short)hh;
          a1[q] = (short)f2bf(f[q] - bf2f(hh));
        }
#pragma unroll
        for (int j = 0; j < 2; ++j) {
          acc[i][j] = __builtin_amdgcn_mfma_f32_16x16x32_bf16(a0, bf[j][0], acc[i][j], 0, 0, 0);
          acc[i][j] = __builtin_amdgcn_mfma_f32_16x16x32_bf16(a0, bf[j][1], acc[i][j], 0, 0, 0);
          acc[i][j] = __builtin_amdgcn_mfma_f32_16x16x32_bf16(a1, bf[j][0], acc[i][j], 0, 0, 0);
        }
      }
    }
    __syncthreads();
  }

#pragma unroll
  for (int i = 0; i < 2; ++i)
#pragma unroll
    for (int j = 0; j < 2; ++j)
#pragma unroll
      for (int r = 0; r < 4; ++r) {
        int row = m0 + wm + i * 16 + quad * 4 + r;
        int c   = n0 + wn + j * 16 + col;
        float v = acc[i][j][r];
        S   [(size_t)row * PROJ_DIM + c] = v;
        Sf16[(size_t)row * PROJ_DIM + c] = f2h(v);
      }
}

// ---------------------------------------------------------------------------
// sim_topk: B-resident + A double-buffer pipeline (prefetch BEFORE compute).
// Block = 64 heads x 128 rows, 256 thr (4 waves, 2x2 grid, wave 64x32).
// LDS: smB 64x256 f16 (32 KB, staged once) + smA dbuf 2 x (128x32) f16
// (2x8 KB) = 48 KB -> 3 blocks/CU. K-loop: 8 chunks of BK=32; GLDS for
// chunk c+1 issued before compute of chunk c, so the barrier's vmcnt(0)
// drain waits only the residual latency. Grid (256 hc, 16 rb) -> hc-major
// for XCD-disjoint mem slices. Epilogue: per (row, 16-lane group) top-1
// (shfl argmax) -> part2[row][hc*2+wcol], 512 group-maxima per row.
// ---------------------------------------------------------------------------
__global__ __launch_bounds__(256) void sim_topk(
    const unsigned short* __restrict__ Af16,   // s_f16 [2048][256]
    const unsigned short* __restrict__ Bf16,   // mem_f16 [16384][256]
    float2* __restrict__ part2)                // [2048][512]
{
  __shared__ __align__(16) unsigned short smB[64 * 256];      // 32 KB
  __shared__ __align__(16) unsigned short smA[2][128 * 32];   // 2 x 8 KB
  const int tid = threadIdx.x;
  const int lane = tid & 63, w = tid >> 6;
  const int quad = lane >> 4, col = lane & 15;
  const int wrow = w >> 1, wcol = w & 1;     // 2x2 wave grid
  const int hc = blockIdx.x;
  const int h0 = hc * 64;
  const int m0 = blockIdx.y * 128;

  // ---- stage B panel (64 heads x full K): 2048 granules, 8/thread ----
#pragma unroll
  for (int t = 0; t < 8; ++t) {
    int P = t * 256 + tid;
    int head = P >> 5, phys = P & 31;
    int slot = phys ^ (head & 31);
    GLDS16(Bf16 + (size_t)(h0 + head) * PROJ_DIM + slot * 8, &smB[P * 8]);
  }
  // ---- stage A chunk 0: 512 granules, 2/thread ----
#pragma unroll
  for (int t = 0; t < 2; ++t) {
    int P = t * 256 + tid;
    int row = P >> 2, phys = P & 3;
    int slot = phys ^ (row & 3);
    GLDS16(Af16 + (size_t)(m0 + row) * PROJ_DIM + slot * 8, &smA[0][P * 8]);
  }

  floatx4 acc[4][2];
#pragma unroll
  for (int i = 0; i < 4; ++i)
#pragma unroll
    for (int j = 0; j < 2; ++j) {
      acc[i][j][0] = 0.f; acc[i][j][1] = 0.f;
      acc[i][j][2] = 0.f; acc[i][j][3] = 0.f;
    }
  __syncthreads();   // B + A chunk 0 ready

  for (int c = 0; c < 8; ++c) {
    // prefetch next A chunk FIRST (different buffer; prev reads done at the
    // barrier that ended iteration c-1)
    if (c < 7) {
#pragma unroll
      for (int t = 0; t < 2; ++t) {
        int P = t * 256 + tid;
        int row = P >> 2, phys = P & 3;
        int slot = phys ^ (row & 3);
        GLDS16(Af16 + (size_t)(m0 + row) * PROJ_DIM + (c + 1) * 32 + slot * 8,
               &smA[(c + 1) & 1][P * 8]);
      }
    }
    const unsigned short* bufA = smA[c & 1];
    half8 a[4], b[2];
#pragma unroll
    for (int i = 0; i < 4; ++i) {
      int rr = wrow * 64 + i * 16 + col;
      int phys = quad ^ (rr & 3);
      a[i] = *(const half8*)&bufA[rr * 32 + phys * 8];
    }
#pragma unroll
    for (int j = 0; j < 2; ++j) {
      int hr = wcol * 32 + j * 16 + col;
      int k8 = c * 4 + quad;
      int phys = k8 ^ (hr & 31);
      b[j] = *(const half8*)&smB[hr * 256 + phys * 8];
    }
#pragma unroll
    for (int i = 0; i < 4; ++i)
#pragma unroll
      for (int j = 0; j < 2; ++j)
        acc[i][j] = __builtin_amdgcn_mfma_f32_16x16x32_f16(a[i], b[j], acc[i][j], 0, 0, 0);
    __syncthreads();   // publishes chunk c+1; drain mostly hidden by compute
  }

  // ---- epilogue: per (row) top-1 of this wave's 32 heads ----
#pragma unroll
  for (int i = 0; i < 4; ++i)
#pragma unroll
    for (int r = 0; r < 4; ++r) {
      float b1 = acc[i][0][r]; int h1 = h0 + wcol * 32 + col;
      {
        float v = acc[i][1][r]; int h = h1 + 16;
        if (v > b1) { b1 = v; h1 = h; }
      }
#pragma unroll
      for (int m = 1; m <= 8; m <<= 1) {
        float ob = __shfl_xor(b1, m); int oh = __shfl_xor(h1, m);
        if (ob > b1 || (ob == b1 && oh < h1)) { b1 = ob; h1 = oh; }
      }
      if (col == 0) {
        int row = m0 + wrow * 64 + i * 16 + quad * 4 + r;
        part2[(size_t)row * 512 + hc * 2 + wcol] =
            make_float2(b1, __int_as_float(h1));
      }
    }
}

// ---------------------------------------------------------------------------
// finalize: 512 group-maxima/row -> global top-4 (4 rounds of wave-argmax +
// mask), exact fp32 rescore of all 4, pick winner, gather logits row.
// ---------------------------------------------------------------------------
__global__ __launch_bounds__(64) void finalize(
    const float2* __restrict__ part2, const float* __restrict__ S,
    const float* __restrict__ Mem, const float* __restrict__ logits,
    float* __restrict__ out)
{
  const int row  = blockIdx.x;
  const int lane = threadIdx.x;

  float v[8]; int c[8];
#pragma unroll
  for (int t = 0; t < 8; ++t) {
    float2 p = part2[(size_t)row * 512 + t * 64 + lane];
    v[t] = p.x; c[t] = __float_as_int(p.y);
  }

  int cand[4];
#pragma unroll
  for (int t = 0; t < 4; ++t) {
    float lv = v[0]; int lh = c[0];
#pragma unroll
    for (int q = 1; q < 8; ++q)
      if (v[q] > lv || (v[q] == lv && c[q] < lh)) { lv = v[q]; lh = c[q]; }
#pragma unroll
    for (int d = 32; d; d >>= 1) {
      float ov = __shfl_xor(lv, d); int oh = __shfl_xor(lh, d);
      if (ov > lv || (ov == lv && oh < lh)) { lv = ov; lh = oh; }
    }
    cand[t] = lh;
#pragma unroll
    for (int q = 0; q < 8; ++q)
      if (c[q] == lh) v[q] = -3.4e38f;
  }

  // exact fp32 rescore of the 4 candidates (lane owns 4 k's)
  float4 sv = ((const float4*)(S + (size_t)row * PROJ_DIM))[lane];
  float bestv = -3.4e38f; int besth = 0x7fffffff;
#pragma unroll
  for (int t = 0; t < 4; ++t) {
    float4 mv = ((const float4*)(Mem + (size_t)cand[t] * PROJ_DIM))[lane];
    float d = sv.x * mv.x + sv.y * mv.y + sv.z * mv.z + sv.w * mv.w;
#pragma unroll
    for (int s = 32; s; s >>= 1) d += __shfl_xor(d, s);
    if (d > bestv || (d == bestv && cand[t] < besth)) { bestv = d; besth = cand[t]; }
  }
  out[(size_t)row * ACT_DIM + lane] = logits[(size_t)besth * ACT_DIM + lane];
}

// ---------------------------------------------------------------------------
extern "C" void kernel_launch(void* const* d_in, const int* in_sizes, int n_in,
                              void* d_out, int out_size, void* d_ws, size_t ws_size,
                              hipStream_t stream) {
  const float* state  = (const float*)d_in[0]; // [2048, 512]
  const float* rp     = (const float*)d_in[1]; // [512, 256]
  const float* mem    = (const float*)d_in[2]; // [16384, 256]
  const float* logits = (const float*)d_in[3]; // [16384, 64]
  float* out = (float*)d_out;                  // [2048, 64]

  // workspace (20 MB):
  //   [0, 0.25)M   rpT_hi  [256][512] bf16
  //   [0.25, 0.5)M rpT_mid
  //   [1, 9)M      mem_f16 [16384][256] f16
  //   [9, 11)M     s       [2048][256] fp32
  //   [11, 12)M    s_f16   [2048][256] f16
  //   [12, 20)M    part2   [2048][512] float2 (8 MB)
  char* ws = (char*)d_ws;
  unsigned short* rpT_hi  = (unsigned short*)(ws);
  unsigned short* rpT_mid = (unsigned short*)(ws + (256u << 10));
  unsigned short* mem_f16 = (unsigned short*)(ws + (1u  << 20));
  float*          s       = (float*)(ws + (9u  << 20));
  unsigned short* s_f16   = (unsigned short*)(ws + (11u << 20));
  float2*         part2   = (float2*)(ws + (12u << 20));

  prep<<<32, 256, 0, stream>>>(rp, rpT_hi, rpT_mid);

  gemm_conv<<<2176, 256, 0, stream>>>(state, rpT_hi, rpT_mid, mem,
                                      s, s_f16, mem_f16);

  sim_topk<<<dim3(256, 16), 256, 0, stream>>>(s_f16, mem_f16, part2);

  finalize<<<BATCH, 64, 0, stream>>>(part2, s, mem, logits, out);
}

// Round 13
// 126.938 us; speedup vs baseline: 1.2507x; 1.2507x over previous
//
#include <hip/hip_runtime.h>

#define BATCH    2048
#define FLAT_IN  512
#define PROJ_DIM 256
#define HEADS    16384
#define ACT_DIM  64

typedef __attribute__((ext_vector_type(8))) short short8;   // 8 bf16/f16 bits
typedef _Float16 half8 __attribute__((ext_vector_type(8))); // 8 f16 (4 VGPR)
typedef __attribute__((ext_vector_type(4))) float floatx4;  // MFMA C/D

__device__ __forceinline__ unsigned short f2bf(float x) {
  unsigned u = __float_as_uint(x);
  u += 0x7fff + ((u >> 16) & 1);
  return (unsigned short)(u >> 16);
}
__device__ __forceinline__ float bf2f(unsigned short b) {
  return __uint_as_float(((unsigned)b) << 16);
}
__device__ __forceinline__ unsigned short f2h(float x) {
  _Float16 h = (_Float16)x;   // RNE
  return __builtin_bit_cast(unsigned short, h);
}

#define GLDS16(g, l)                                                          \
  __builtin_amdgcn_global_load_lds(                                           \
      (__attribute__((address_space(1))) void*)(void*)(g),                    \
      (__attribute__((address_space(3))) void*)(l), 16, 0, 0)

// ---------------------------------------------------------------------------
// prep (R11-proven): [0,1024) split state -> st_hi/st_mid bf16;
// [1024,1056) transpose+split rp -> rpT_hi/mid.
// ---------------------------------------------------------------------------
__global__ __launch_bounds__(256) void prep(
    const float* __restrict__ state, const float* __restrict__ rp,
    unsigned short* __restrict__ st_hi, unsigned short* __restrict__ st_mid,
    unsigned short* __restrict__ rpT_hi, unsigned short* __restrict__ rpT_mid)
{
  const int tid = threadIdx.x;
  const int b = blockIdx.x;
  if (b < 1024) {
    int i = b * 256 + tid;
    float4 v = ((const float4*)state)[i];
    ushort4 h, m;
    h.x = f2bf(v.x); m.x = f2bf(v.x - bf2f(h.x));
    h.y = f2bf(v.y); m.y = f2bf(v.y - bf2f(h.y));
    h.z = f2bf(v.z); m.z = f2bf(v.z - bf2f(h.z));
    h.w = f2bf(v.w); m.w = f2bf(v.w - bf2f(h.w));
    ((ushort4*)st_hi)[i]  = h;
    ((ushort4*)st_mid)[i] = m;
  } else {
    __shared__ float t[64][65];
    int bid = b - 1024;
    int k0 = (bid >> 2) * 64, n0 = (bid & 3) * 64;
#pragma unroll
    for (int it = 0; it < 16; ++it) {
      int lin = it * 256 + tid;
      int kr = lin >> 6, nc = lin & 63;
      t[kr][nc] = rp[(size_t)(k0 + kr) * PROJ_DIM + n0 + nc];
    }
    __syncthreads();
#pragma unroll
    for (int it = 0; it < 16; ++it) {
      int lin = it * 256 + tid;
      int nr = lin >> 6, kc = lin & 63;
      float v = t[kc][nr];
      unsigned short hh = f2bf(v);
      rpT_hi [(size_t)(n0 + nr) * FLAT_IN + k0 + kc] = hh;
      rpT_mid[(size_t)(n0 + nr) * FLAT_IN + k0 + kc] = f2bf(v - bf2f(hh));
    }
  }
}

// ---------------------------------------------------------------------------
// gemm_conv (R11-proven): blocks [0,128) = gemm (s = state @ rp, 3-term
// split-bf16 MFMA, GLDS staging, tile 64x64, BK=64); blocks [128,2176) =
// mem fp32 -> f16 conversion (fills the CUs gemm leaves idle).
// ---------------------------------------------------------------------------
__global__ __launch_bounds__(256, 2) void gemm_conv(
    const unsigned short* __restrict__ Ahi, const unsigned short* __restrict__ Amid,
    const unsigned short* __restrict__ Bhi, const unsigned short* __restrict__ Bmid,
    const float* __restrict__ mem,
    float* __restrict__ S, unsigned short* __restrict__ Sf16,
    unsigned short* __restrict__ mem_f16)
{
  const int tid = threadIdx.x;
  if (blockIdx.x >= 128) {
    // ---- conversion path ----
    int i2 = (blockIdx.x - 128) * 256 + tid;   // 8-float granule index
    float4 x = ((const float4*)mem)[2 * i2];
    float4 y = ((const float4*)mem)[2 * i2 + 1];
    short8 o;
    o[0] = (short)f2h(x.x); o[1] = (short)f2h(x.y);
    o[2] = (short)f2h(x.z); o[3] = (short)f2h(x.w);
    o[4] = (short)f2h(y.x); o[5] = (short)f2h(y.y);
    o[6] = (short)f2h(y.z); o[7] = (short)f2h(y.w);
    ((short8*)mem_f16)[i2] = o;
    return;
  }

  // ---- gemm path ----
  __shared__ __align__(16) unsigned short sm[4][64 * 64];
  const int lane = tid & 63, w = tid >> 6;
  const int quad = lane >> 4, col = lane & 15;
  const int wm = (w >> 1) * 32, wn = (w & 1) * 32;
  const int g = blockIdx.x;
  const int m0 = (g & 31) * 64, n0 = (g >> 5) * 64;

  floatx4 acc[2][2];
#pragma unroll
  for (int i = 0; i < 2; ++i)
#pragma unroll
    for (int j = 0; j < 2; ++j) {
      acc[i][j][0] = 0.f; acc[i][j][1] = 0.f;
      acc[i][j][2] = 0.f; acc[i][j][3] = 0.f;
    }

  const int P0 = tid, P1 = tid + 256;
  const int r0 = P0 >> 3, kl0 = (P0 & 7) ^ (r0 & 7);
  const int r1 = P1 >> 3, kl1 = (P1 & 7) ^ (r1 & 7);

  for (int kc = 0; kc < FLAT_IN; kc += 64) {
    GLDS16(Ahi  + (size_t)(m0 + r0) * FLAT_IN + kc + kl0 * 8, &sm[0][P0 * 8]);
    GLDS16(Ahi  + (size_t)(m0 + r1) * FLAT_IN + kc + kl1 * 8, &sm[0][P1 * 8]);
    GLDS16(Amid + (size_t)(m0 + r0) * FLAT_IN + kc + kl0 * 8, &sm[1][P0 * 8]);
    GLDS16(Amid + (size_t)(m0 + r1) * FLAT_IN + kc + kl1 * 8, &sm[1][P1 * 8]);
    GLDS16(Bhi  + (size_t)(n0 + r0) * FLAT_IN + kc + kl0 * 8, &sm[2][P0 * 8]);
    GLDS16(Bhi  + (size_t)(n0 + r1) * FLAT_IN + kc + kl1 * 8, &sm[2][P1 * 8]);
    GLDS16(Bmid + (size_t)(n0 + r0) * FLAT_IN + kc + kl0 * 8, &sm[3][P0 * 8]);
    GLDS16(Bmid + (size_t)(n0 + r1) * FLAT_IN + kc + kl1 * 8, &sm[3][P1 * 8]);
    __syncthreads();

#pragma unroll
    for (int ks = 0; ks < 2; ++ks) {
      short8 bf[2][2];
#pragma unroll
      for (int j = 0; j < 2; ++j) {
        int rr = wn + j * 16 + col;
        int off = rr * 64 + (((ks * 4 + quad) ^ (rr & 7)) * 8);
        bf[j][0] = *(const short8*)&sm[2][off];
        bf[j][1] = *(const short8*)&sm[3][off];
      }
#pragma unroll
      for (int i = 0; i < 2; ++i) {
        int rr = wm + i * 16 + col;
        int off = rr * 64 + (((ks * 4 + quad) ^ (rr & 7)) * 8);
        short8 a0 = *(const short8*)&sm[0][off];
        short8 a1 = *(const short8*)&sm[1][off];
#pragma unroll
        for (int j = 0; j < 2; ++j) {
          acc[i][j] = __builtin_amdgcn_mfma_f32_16x16x32_bf16(a0, bf[j][0], acc[i][j], 0, 0, 0);
          acc[i][j] = __builtin_amdgcn_mfma_f32_16x16x32_bf16(a0, bf[j][1], acc[i][j], 0, 0, 0);
          acc[i][j] = __builtin_amdgcn_mfma_f32_16x16x32_bf16(a1, bf[j][0], acc[i][j], 0, 0, 0);
        }
      }
    }
    __syncthreads();
  }

#pragma unroll
  for (int i = 0; i < 2; ++i)
#pragma unroll
    for (int j = 0; j < 2; ++j)
#pragma unroll
      for (int r = 0; r < 4; ++r) {
        int row = m0 + wm + i * 16 + quad * 4 + r;
        int c   = n0 + wn + j * 16 + col;
        float v = acc[i][j][r];
        S   [(size_t)row * PROJ_DIM + c] = v;
        Sf16[(size_t)row * PROJ_DIM + c] = f2h(v);
      }
}

// ---------------------------------------------------------------------------
// sim_topk: m103-sweet-spot 128x128 tile, BK=64, 256 thr (4 waves 2x2, wave
// 64x64), GLDS staging, zero-conflict R5/R11 fragment indexing. LDS 32 KB ->
// 5 blocks/CU (20 waves/CU) for drain hiding. Grid (128 hc, 16 rb), hc-major
// -> per-XCD mem slice 1 MB (L2-resident). Cheap epilogue: per (row, 16-lane
// group) top-1 (shfl argmax) -> part2[row][hc*2 + (w&1)], 256 maxima/row.
// ---------------------------------------------------------------------------
__global__ __launch_bounds__(256) void sim_topk(
    const unsigned short* __restrict__ Af16,   // s_f16 [2048][256]
    const unsigned short* __restrict__ Bf16,   // mem_f16 [16384][256]
    float2* __restrict__ part2)                // [2048][256]
{
  __shared__ __align__(16) unsigned short smA[128 * 64];  // 16 KB
  __shared__ __align__(16) unsigned short smB[128 * 64];  // 16 KB
  const int tid = threadIdx.x;
  const int lane = tid & 63, w = tid >> 6;
  const int quad = lane >> 4, col = lane & 15;
  const int wm = (w >> 1) * 64, wn = (w & 1) * 64;
  const int hc = blockIdx.x;            // 0..127, fast-varying -> XCD
  const int h0 = hc * 128;
  const int m0 = blockIdx.y * 128;

  floatx4 acc[4][4];
#pragma unroll
  for (int i = 0; i < 4; ++i)
#pragma unroll
    for (int j = 0; j < 4; ++j) {
      acc[i][j][0] = 0.f; acc[i][j][1] = 0.f;
      acc[i][j][2] = 0.f; acc[i][j][3] = 0.f;
    }

  // staging: 1024 granules (16B) per matrix, 4/thread each.
  // granule P: row = P>>3, phys slot = P&7, logical k-slot = phys^(row&7).
  int rg[4], kg[4];
#pragma unroll
  for (int t = 0; t < 4; ++t) {
    int P = t * 256 + tid;
    rg[t] = P >> 3; kg[t] = (P & 7) ^ (rg[t] & 7);
  }

  for (int kc = 0; kc < PROJ_DIM; kc += 64) {
#pragma unroll
    for (int t = 0; t < 4; ++t)
      GLDS16(Af16 + (size_t)(m0 + rg[t]) * PROJ_DIM + kc + kg[t] * 8,
             &smA[(t * 256 + tid) * 8]);
#pragma unroll
    for (int t = 0; t < 4; ++t)
      GLDS16(Bf16 + (size_t)(h0 + rg[t]) * PROJ_DIM + kc + kg[t] * 8,
             &smB[(t * 256 + tid) * 8]);
    __syncthreads();

#pragma unroll
    for (int ks = 0; ks < 2; ++ks) {
      half8 a[4], bfr[4];
#pragma unroll
      for (int i = 0; i < 4; ++i) {
        int rr = wm + i * 16 + col;
        int off = rr * 64 + (((ks * 4 + quad) ^ (rr & 7)) * 8);
        a[i] = *(const half8*)&smA[off];
      }
#pragma unroll
      for (int j = 0; j < 4; ++j) {
        int rr = wn + j * 16 + col;
        int off = rr * 64 + (((ks * 4 + quad) ^ (rr & 7)) * 8);
        bfr[j] = *(const half8*)&smB[off];
      }
#pragma unroll
      for (int i = 0; i < 4; ++i)
#pragma unroll
        for (int j = 0; j < 4; ++j)
          acc[i][j] = __builtin_amdgcn_mfma_f32_16x16x32_f16(a[i], bfr[j], acc[i][j], 0, 0, 0);
    }
    __syncthreads();
  }

  // ---- cheap epilogue: per (row) top-1 of this wave's 64 heads ----
#pragma unroll
  for (int i = 0; i < 4; ++i)
#pragma unroll
    for (int r = 0; r < 4; ++r) {
      float b1 = acc[i][0][r]; int h1 = h0 + wn + col;
#pragma unroll
      for (int j = 1; j < 4; ++j) {
        float v = acc[i][j][r]; int h = h0 + wn + j * 16 + col;
        if (v > b1) { b1 = v; h1 = h; }
      }
#pragma unroll
      for (int m = 1; m <= 8; m <<= 1) {
        float ob = __shfl_xor(b1, m); int oh = __shfl_xor(h1, m);
        if (ob > b1 || (ob == b1 && oh < h1)) { b1 = ob; h1 = oh; }
      }
      if (col == 0) {
        int row = m0 + wm + i * 16 + quad * 4 + r;
        part2[(size_t)row * 256 + hc * 2 + (w & 1)] =
            make_float2(b1, __int_as_float(h1));
      }
    }
}

// ---------------------------------------------------------------------------
// finalize: 4 rows per block (one per wave), 512 blocks x 256 thr.
// 256 group-maxima/row -> global top-4 (4 rounds of wave-argmax + mask),
// exact fp32 rescore of all 4, pick winner, gather logits row.
// ---------------------------------------------------------------------------
__global__ __launch_bounds__(256) void finalize(
    const float2* __restrict__ part2, const float* __restrict__ S,
    const float* __restrict__ Mem, const float* __restrict__ logits,
    float* __restrict__ out)
{
  const int w    = threadIdx.x >> 6;
  const int lane = threadIdx.x & 63;
  const int row  = blockIdx.x * 4 + w;

  float v[4]; int c[4];
#pragma unroll
  for (int t = 0; t < 4; ++t) {
    float2 p = part2[(size_t)row * 256 + t * 64 + lane];
    v[t] = p.x; c[t] = __float_as_int(p.y);
  }

  int cand[4];
#pragma unroll
  for (int t = 0; t < 4; ++t) {
    float lv = v[0]; int lh = c[0];
#pragma unroll
    for (int q = 1; q < 4; ++q)
      if (v[q] > lv || (v[q] == lv && c[q] < lh)) { lv = v[q]; lh = c[q]; }
#pragma unroll
    for (int d = 32; d; d >>= 1) {
      float ov = __shfl_xor(lv, d); int oh = __shfl_xor(lh, d);
      if (ov > lv || (ov == lv && oh < lh)) { lv = ov; lh = oh; }
    }
    cand[t] = lh;
#pragma unroll
    for (int q = 0; q < 4; ++q)
      if (c[q] == lh) v[q] = -3.4e38f;
  }

  // exact fp32 rescore of the 4 candidates (lane owns 4 k's)
  float4 sv = ((const float4*)(S + (size_t)row * PROJ_DIM))[lane];
  float bestv = -3.4e38f; int besth = 0x7fffffff;
#pragma unroll
  for (int t = 0; t < 4; ++t) {
    float4 mv = ((const float4*)(Mem + (size_t)cand[t] * PROJ_DIM))[lane];
    float d = sv.x * mv.x + sv.y * mv.y + sv.z * mv.z + sv.w * mv.w;
#pragma unroll
    for (int s = 32; s; s >>= 1) d += __shfl_xor(d, s);
    if (d > bestv || (d == bestv && cand[t] < besth)) { bestv = d; besth = cand[t]; }
  }
  out[(size_t)row * ACT_DIM + lane] = logits[(size_t)besth * ACT_DIM + lane];
}

// ---------------------------------------------------------------------------
extern "C" void kernel_launch(void* const* d_in, const int* in_sizes, int n_in,
                              void* d_out, int out_size, void* d_ws, size_t ws_size,
                              hipStream_t stream) {
  const float* state  = (const float*)d_in[0]; // [2048, 512]
  const float* rp     = (const float*)d_in[1]; // [512, 256]
  const float* mem    = (const float*)d_in[2]; // [16384, 256]
  const float* logits = (const float*)d_in[3]; // [16384, 64]
  float* out = (float*)d_out;                  // [2048, 64]

  // workspace (24 MB):
  //   [0, 2)M     st_hi  [2048][512] bf16
  //   [2, 4)M     st_mid
  //   [4, 4.25)M  rpT_hi [256][512] bf16
  //   [4.25,4.5)M rpT_mid
  //   [8, 16)M    mem_f16 [16384][256] f16
  //   [16,18)M    s      [2048][256] fp32
  //   [18,19)M    s_f16  [2048][256] f16
  //   [20,24)M    part2  [2048][256] float2 (4 MB)
  char* ws = (char*)d_ws;
  unsigned short* st_hi   = (unsigned short*)(ws);
  unsigned short* st_mid  = (unsigned short*)(ws + (2u  << 20));
  unsigned short* rpT_hi  = (unsigned short*)(ws + (4u  << 20));
  unsigned short* rpT_mid = (unsigned short*)(ws + (4u  << 20) + (256u << 10));
  unsigned short* mem_f16 = (unsigned short*)(ws + (8u  << 20));
  float*          s       = (float*)(ws + (16u << 20));
  unsigned short* s_f16   = (unsigned short*)(ws + (18u << 20));
  float2*         part2   = (float2*)(ws + (20u << 20));

  prep<<<1056, 256, 0, stream>>>(state, rp, st_hi, st_mid, rpT_hi, rpT_mid);

  gemm_conv<<<2176, 256, 0, stream>>>(st_hi, st_mid, rpT_hi, rpT_mid, mem,
                                      s, s_f16, mem_f16);

  sim_topk<<<dim3(128, 16), 256, 0, stream>>>(s_f16, mem_f16, part2);

  finalize<<<512, 256, 0, stream>>>(part2, s, mem, logits, out);
}